// Round 13
// baseline (353.631 us; speedup 1.0000x reference)
//
#include <hip/hip_runtime.h>

#define N_NODES  50000
#define N_EDGES  600000
#define N_GRAPHS 512
#define DIM      128
#define N_FEAT   78
#define N_LAYERS 4
#define BN_EPS   1e-5f
#define SLOT_CAP 64
#define LDA      136
#define NPART    32

#define NBKT     196                          // ceil(50000/256) dst-range buckets
#define NBLK_BIN 128                          // bin blocks (private regions each)
#define BCAP     64                           // per-(block,bucket) cap: mean 24, +8 sigma
#define EDGES_PER_BIN ((N_EDGES + NBLK_BIN - 1) / NBLK_BIN)   // 4688

#define GSTART_BLOCKS 196                     // boundary scan over sorted batch
#define ZERO_BLOCKS 512                       // zero 2 MB of gsum+gssq
#define GBLOCKS ((N_NODES + 63) / 64)         // 782 (ini tile = 64 rows)
#define GIN_BLOCKS ((N_NODES + 31) / 32)      // 1563 (gin tile = 32 rows)
#define TW_ELEMS (10 * 16384)
#define BN_FLOATS (N_LAYERS * NPART * 256)    // 32768
#define TWB ((TW_ELEMS + BN_FLOATS + 255) / 256)   // 768

typedef __attribute__((ext_vector_type(8))) _Float16 f16x8;
typedef __attribute__((ext_vector_type(4))) float f32x4;

static __device__ __forceinline__ short f2h(float f) {
    _Float16 h = (_Float16)f;
    union { _Float16 h; short s; } u; u.h = h;
    return u.s;
}
static __device__ __forceinline__ float h2f(ushort s) {
    union { ushort s; _Float16 h; } u; u.s = s;
    return (float)u.h;
}

// ---------------- prep: weight transpose + bnstat zero + edge binning + gstart + zero ----

__global__ __launch_bounds__(256) void prep(const float* __restrict__ ini_w1,
                                            const float* __restrict__ ini_w2,
                                            const float* __restrict__ gw1,
                                            const float* __restrict__ gw2,
                                            short* __restrict__ wt,
                                            float* __restrict__ bnstat,
                                            const int* __restrict__ src,
                                            const int* __restrict__ dst,
                                            const int* __restrict__ batch,
                                            int* __restrict__ bcnt,
                                            uint* __restrict__ bpool,
                                            int* __restrict__ gstart,
                                            float* __restrict__ gsum,
                                            float* __restrict__ gssq) {
    __shared__ int lcur[NBKT];
    int tid = threadIdx.x;
    int b = blockIdx.x;
    if (b < TWB) {
        int gid = b * 256 + tid;
        if (gid < TW_ELEMS) {
            int m = gid >> 14;
            int idx = gid & 16383;
            int n = idx >> 7;
            int k = idx & 127;
            const float* s;
            int K = 128;
            if (m == 0) { s = ini_w1; K = N_FEAT; }
            else if (m == 1) s = ini_w2;
            else if (m < 6) s = gw1 + (m - 2) * 16384;
            else s = gw2 + (m - 6) * 16384;
            float v = (k < K) ? s[k * 128 + n] : 0.f;
            wt[m * 16384 + n * 128 + k] = f2h(v);
        } else {
            int bi = gid - TW_ELEMS;
            if (bi < BN_FLOATS) bnstat[bi] = 0.0f;
        }
        return;
    }
    b -= TWB;
    if (b < NBLK_BIN) {
        for (int i = tid; i < NBKT; i += 256) lcur[i] = 0;
        __syncthreads();
        int base = b * EDGES_PER_BIN;
        int lim = min(base + EDGES_PER_BIN, N_EDGES);
        for (int e = base + tid; e < lim; e += 256) {
            int d = dst[e];
            int s = src[e];
            int bk = d >> 8;
            int p = atomicAdd(&lcur[bk], 1);
            if (p < BCAP)
                bpool[(bk * NBLK_BIN + b) * BCAP + p] =
                    ((uint)(d & 255) << 16) | (uint)s;
        }
        __syncthreads();
        for (int i = tid; i < NBKT; i += 256) bcnt[b * NBKT + i] = lcur[i];
        return;
    }
    b -= NBLK_BIN;
    if (b < GSTART_BLOCKS) {
        int n = b * 256 + tid;
        if (n < N_NODES) {
            int g = batch[n];
            int gp = (n == 0) ? -1 : batch[n - 1];
            for (int gg = gp + 1; gg <= g; ++gg) gstart[gg] = n;
            if (n == N_NODES - 1)
                for (int gg = g + 1; gg <= N_GRAPHS; ++gg) gstart[gg] = N_NODES;
        }
        return;
    }
    b -= GSTART_BLOCKS;
    float4 z = make_float4(0.f, 0.f, 0.f, 0.f);
    float* bse = (b < 256) ? gsum : gssq;
    int off = (b & 255) * 1024 + tid * 4;
    *(float4*)&bse[off] = z;
}

// ---------------- fused: initial MLP (blocks < GBLOCKS) + slot build (rest) -------

__global__ __launch_bounds__(256, 4) void ini_fused(const float* __restrict__ x,
                                                    const short* __restrict__ Wt1,
                                                    const float* __restrict__ b1,
                                                    const short* __restrict__ Wt2,
                                                    const float* __restrict__ b2,
                                                    ushort* __restrict__ Cout,
                                                    const uint* __restrict__ bpool,
                                                    const int* __restrict__ bcnt,
                                                    int* __restrict__ cnt,
                                                    ushort* __restrict__ slot) {
    __shared__ short smem[2 * 64 * LDA];   // 34816 B, aliased per block role
    int tid = threadIdx.x;

    if (blockIdx.x >= GBLOCKS) {
        // ---- slot-build part ----
        int bkt = blockIdx.x - GBLOCKS;
        ushort* lslot = (ushort*)smem;                     // 32768 B
        int* lcnt = (int*)((char*)smem + 32768);           // 1024 B
        int* rcnt = (int*)((char*)smem + 33792);           // 512 B
        lcnt[tid] = 0;
        if (tid < NBLK_BIN) rcnt[tid] = min(bcnt[tid * NBKT + bkt], BCAP);
        __syncthreads();
        const uint* pool = bpool + (size_t)bkt * NBLK_BIN * BCAP;
        #pragma unroll 1
        for (int i = tid; i < NBLK_BIN * BCAP; i += 256) {
            int run = i >> 6;
            int pos = i & (BCAP - 1);
            if (pos < rcnt[run]) {
                uint u = pool[i];
                int ls = u >> 16;
                int p = atomicAdd(&lcnt[ls], 1);
                if (p < SLOT_CAP) lslot[ls * SLOT_CAP + p] = (ushort)(u & 0xffffu);
            }
        }
        __syncthreads();
        int node0 = bkt << 8;
        int gn = node0 + tid;
        if (gn < N_NODES) cnt[gn] = lcnt[tid];
        #pragma unroll
        for (int j = 0; j < 8; ++j) {
            int i = tid + j * 256;
            int r = i >> 3;
            int c = i & 7;
            int g = node0 + r;
            if (g < N_NODES)
                *(uint4*)&slot[g * SLOT_CAP + c * 8] = *(const uint4*)&lslot[r * SLOT_CAP + c * 8];
        }
        return;
    }

    // ---- gemm_ini part: C = relu(A@W1+b1)@W2+b2, A fp32 [N,78] ----
    short* As = smem;
    short* Bs = smem + 64 * LDA;
    int row0 = blockIdx.x * 64;
    int wave = tid >> 6;
    int wlane = tid & 63;
    int rw = wave >> 1;
    int cw = wave & 1;
    int lm = wlane & 15;
    int quad = wlane >> 4;
    const int wrow = (cw * 64 + lm) * 128 + quad * 8;

    f16x8 bcur[4], bnxt[4];
    #pragma unroll
    for (int nt = 0; nt < 4; ++nt)
        bcur[nt] = *(const f16x8*)&Wt1[wrow + nt * 2048];

    #pragma unroll
    for (int j = 0; j < 32; ++j) {
        int lin = tid + j * 256;
        int r = lin >> 7;
        int k = lin & 127;
        int gr = row0 + r;
        float v = 0.f;
        if (gr < N_NODES && k < N_FEAT) v = x[gr * N_FEAT + k];
        As[r * LDA + k] = f2h(v);
    }
    __syncthreads();   // As ready

    f32x4 acc[2][4];
    #pragma unroll
    for (int mt = 0; mt < 2; ++mt)
        #pragma unroll
        for (int nt = 0; nt < 4; ++nt)
            acc[mt][nt] = (f32x4){0.f, 0.f, 0.f, 0.f};

    #pragma unroll
    for (int ks = 0; ks < 4; ++ks) {
        if (ks < 3) {
            #pragma unroll
            for (int nt = 0; nt < 4; ++nt)
                bnxt[nt] = *(const f16x8*)&Wt1[wrow + nt * 2048 + (ks + 1) * 32];
        }
        int kb = ks * 32 + quad * 8;
        f16x8 a0 = *(const f16x8*)&As[(rw * 32 + lm) * LDA + kb];
        f16x8 a1 = *(const f16x8*)&As[(rw * 32 + 16 + lm) * LDA + kb];
        #pragma unroll
        for (int nt = 0; nt < 4; ++nt) {
            acc[0][nt] = __builtin_amdgcn_mfma_f32_16x16x32_f16(a0, bcur[nt], acc[0][nt], 0, 0, 0);
            acc[1][nt] = __builtin_amdgcn_mfma_f32_16x16x32_f16(a1, bcur[nt], acc[1][nt], 0, 0, 0);
        }
        #pragma unroll
        for (int nt = 0; nt < 4; ++nt) bcur[nt] = bnxt[nt];
    }

    #pragma unroll
    for (int nt = 0; nt < 4; ++nt) {
        int col = cw * 64 + nt * 16 + lm;
        float bv = b1[col];
        #pragma unroll
        for (int mt = 0; mt < 2; ++mt) {
            #pragma unroll
            for (int r = 0; r < 4; ++r) {
                int row = rw * 32 + mt * 16 + quad * 4 + r;
                Bs[row * LDA + col] = (short)f2h(fmaxf(acc[mt][nt][r] + bv, 0.f));
            }
        }
    }
    #pragma unroll
    for (int nt = 0; nt < 4; ++nt)
        bcur[nt] = *(const f16x8*)&Wt2[wrow + nt * 2048];
    __syncthreads();   // Bs ready

    #pragma unroll
    for (int mt = 0; mt < 2; ++mt)
        #pragma unroll
        for (int nt = 0; nt < 4; ++nt)
            acc[mt][nt] = (f32x4){0.f, 0.f, 0.f, 0.f};
    #pragma unroll
    for (int ks = 0; ks < 4; ++ks) {
        if (ks < 3) {
            #pragma unroll
            for (int nt = 0; nt < 4; ++nt)
                bnxt[nt] = *(const f16x8*)&Wt2[wrow + nt * 2048 + (ks + 1) * 32];
        }
        int kb = ks * 32 + quad * 8;
        f16x8 a0 = *(const f16x8*)&Bs[(rw * 32 + lm) * LDA + kb];
        f16x8 a1 = *(const f16x8*)&Bs[(rw * 32 + 16 + lm) * LDA + kb];
        #pragma unroll
        for (int nt = 0; nt < 4; ++nt) {
            acc[0][nt] = __builtin_amdgcn_mfma_f32_16x16x32_f16(a0, bcur[nt], acc[0][nt], 0, 0, 0);
            acc[1][nt] = __builtin_amdgcn_mfma_f32_16x16x32_f16(a1, bcur[nt], acc[1][nt], 0, 0, 0);
        }
        #pragma unroll
        for (int nt = 0; nt < 4; ++nt) bcur[nt] = bnxt[nt];
    }

    ushort* Cs = (ushort*)As;
    #pragma unroll
    for (int nt = 0; nt < 4; ++nt) {
        int col = cw * 64 + nt * 16 + lm;
        float bv = b2[col];
        #pragma unroll
        for (int mt = 0; mt < 2; ++mt) {
            #pragma unroll
            for (int r = 0; r < 4; ++r) {
                int row = rw * 32 + mt * 16 + quad * 4 + r;
                Cs[row * LDA + col] = (ushort)f2h(acc[mt][nt][r] + bv);
            }
        }
    }
    __syncthreads();   // Cs ready

    #pragma unroll
    for (int j = 0; j < 4; ++j) {
        int lin = tid + j * 256;
        int r = lin >> 4;
        int kc = lin & 15;
        int gr = row0 + r;
        if (gr < N_NODES)
            *(uint4*)&Cout[gr * 128 + kc * 8] = *(const uint4*)&Cs[r * LDA + kc * 8];
    }
}

// ---------------- fused GIN layer: aggregation + BN affine -> 2-layer MLP + stats ----
// 32-row tiles (1563 blocks): R11 showed occupancy is GRID-limited (782 blocks /
// 256 CU ~ 3/CU); halving the tile doubles resident blocks -> ~6/CU, ~2x the
// outstanding gathers for the latency-bound phase. LDS ~10 KB, acc[4] per wave
// (1 row-tile x 4 col-tiles), VGPR ~56 unchanged.

__global__ __launch_bounds__(256, 4) void gin_fused(const ushort* __restrict__ Z,
                                                    const int* __restrict__ cnt,
                                                    const ushort* __restrict__ slot,
                                                    const float* __restrict__ bnpart,
                                                    const float* __restrict__ gamma,
                                                    const float* __restrict__ beta,
                                                    const short* __restrict__ Wt1,
                                                    const float* __restrict__ b1,
                                                    const short* __restrict__ Wt2,
                                                    const float* __restrict__ b2,
                                                    ushort* __restrict__ C,
                                                    const int* __restrict__ batch,
                                                    float* __restrict__ gsum,
                                                    float* __restrict__ gssq,
                                                    float* __restrict__ bnpart_out) {
    __shared__ short As[32 * LDA];     // gather out -> GEMM1 in -> P -> GEMM2 in -> C
    __shared__ float saff[128], taff[128];
    __shared__ int sb[32];
    int tid = threadIdx.x;
    int row0 = blockIdx.x * 32;

    int wave = tid >> 6;
    int wlane = tid & 63;
    int rw = wave >> 1;              // row half: rows rw*16 .. rw*16+15
    int cw = wave & 1;               // col half: cols cw*64 .. cw*64+63
    int lm = wlane & 15;
    int quad = wlane >> 4;
    const int wrow = (cw * 64 + lm) * 128 + quad * 8;

    if (tid < 128) {
        float s = 1.0f, t = 0.0f;
        if (bnpart) {
            float sum = 0.f, ssq = 0.f;
            #pragma unroll
            for (int p = 0; p < NPART; ++p) {
                sum += bnpart[p * 256 + tid];
                ssq += bnpart[p * 256 + 128 + tid];
            }
            const float invN = 1.0f / (float)N_NODES;
            float m = sum * invN;
            float var = ssq * invN - m * m;
            s = gamma[tid] * rsqrtf(var + BN_EPS);
            t = beta[tid] - m * s;
        }
        saff[tid] = s; taff[tid] = t;
    }
    if (tid < 32) {
        int n = row0 + tid;
        sb[tid] = (n < N_NODES) ? batch[n] : -1;
    }
    __syncthreads();   // b0: saff/taff ready

    // ---- gather phase: 16 lanes per node, 16 nodes per pass, 2 passes ----
    {
        int lane = tid & 15;
        int nsub = tid >> 4;
        union U { uint4 u; _Float16 h[8]; };
        union I { uint4 u; ushort s[8]; };
        const uint4* z4 = (const uint4*)Z;
        #pragma unroll 1
        for (int pass = 0; pass < 2; ++pass) {
            int r = pass * 16 + nsub;
            int node = row0 + r;
            float v[8];
            float dsc = 1.0f;
            if (node < N_NODES) {
                U zu; zu.u = z4[node * 16 + lane];
                #pragma unroll
                for (int j = 0; j < 8; ++j) v[j] = (float)zu.h[j];
                int dtrue = cnt[node];
                int d = min(dtrue, SLOT_CAP);
                const ushort* sl = slot + node * SLOT_CAP;
                int e = 0;
                for (; e + 8 <= d; e += 8) {
                    I si; si.u = *(const uint4*)&sl[e];
                    U u[8];
                    #pragma unroll
                    for (int q = 0; q < 8; ++q) u[q].u = z4[(int)si.s[q] * 16 + lane];
                    #pragma unroll
                    for (int j = 0; j < 8; ++j) {
                        float a = ((float)u[0].h[j] + (float)u[1].h[j]) +
                                  ((float)u[2].h[j] + (float)u[3].h[j]);
                        float b = ((float)u[4].h[j] + (float)u[5].h[j]) +
                                  ((float)u[6].h[j] + (float)u[7].h[j]);
                        v[j] += a + b;
                    }
                }
                if (e + 4 <= d) {
                    int s0 = sl[e], s1 = sl[e + 1], s2 = sl[e + 2], s3 = sl[e + 3];
                    U u0, u1, u2, u3;
                    u0.u = z4[s0 * 16 + lane];
                    u1.u = z4[s1 * 16 + lane];
                    u2.u = z4[s2 * 16 + lane];
                    u3.u = z4[s3 * 16 + lane];
                    #pragma unroll
                    for (int j = 0; j < 8; ++j)
                        v[j] += ((float)u0.h[j] + (float)u1.h[j]) +
                                ((float)u2.h[j] + (float)u3.h[j]);
                    e += 4;
                }
                for (; e < d; ++e) {
                    U u; u.u = z4[(int)sl[e] * 16 + lane];
                    #pragma unroll
                    for (int j = 0; j < 8; ++j) v[j] += (float)u.h[j];
                }
                dsc = 1.0f + (float)dtrue;
            } else {
                #pragma unroll
                for (int j = 0; j < 8; ++j) v[j] = 0.f;
                dsc = 0.f;
            }
            #pragma unroll
            for (int j = 0; j < 8; ++j) {
                int dd = lane * 8 + j;
                As[r * LDA + dd] = f2h(saff[dd] * v[j] + dsc * taff[dd]);
            }
        }
    }

    f16x8 bcur[4], bnxt[4];
    #pragma unroll
    for (int nt = 0; nt < 4; ++nt)
        bcur[nt] = *(const f16x8*)&Wt1[wrow + nt * 2048];
    __syncthreads();   // b1: As (aggregated A) ready

    // ---- GEMM 1: acc = As @ W1 (full accumulation in registers) ----
    f32x4 acc[4];
    #pragma unroll
    for (int nt = 0; nt < 4; ++nt)
        acc[nt] = (f32x4){0.f, 0.f, 0.f, 0.f};
    #pragma unroll
    for (int ks = 0; ks < 4; ++ks) {
        if (ks < 3) {
            #pragma unroll
            for (int nt = 0; nt < 4; ++nt)
                bnxt[nt] = *(const f16x8*)&Wt1[wrow + nt * 2048 + (ks + 1) * 32];
        }
        int kb = ks * 32 + quad * 8;
        f16x8 a0 = *(const f16x8*)&As[(rw * 16 + lm) * LDA + kb];
        #pragma unroll
        for (int nt = 0; nt < 4; ++nt)
            acc[nt] = __builtin_amdgcn_mfma_f32_16x16x32_f16(a0, bcur[nt], acc[nt], 0, 0, 0);
        #pragma unroll
        for (int nt = 0; nt < 4; ++nt) bcur[nt] = bnxt[nt];
    }
    #pragma unroll
    for (int nt = 0; nt < 4; ++nt)
        bcur[nt] = *(const f16x8*)&Wt2[wrow + nt * 2048];
    __syncthreads();   // b2: ALL As reads done -> safe to overwrite in place

    // P = relu(acc + b1) -> As
    #pragma unroll
    for (int nt = 0; nt < 4; ++nt) {
        int col = cw * 64 + nt * 16 + lm;
        float bv = b1[col];
        #pragma unroll
        for (int r = 0; r < 4; ++r) {
            int row = rw * 16 + quad * 4 + r;
            As[row * LDA + col] = (short)f2h(fmaxf(acc[nt][r] + bv, 0.f));
        }
    }
    __syncthreads();   // b3: P ready

    // ---- GEMM 2: acc = P @ W2 ----
    #pragma unroll
    for (int nt = 0; nt < 4; ++nt)
        acc[nt] = (f32x4){0.f, 0.f, 0.f, 0.f};
    #pragma unroll
    for (int ks = 0; ks < 4; ++ks) {
        if (ks < 3) {
            #pragma unroll
            for (int nt = 0; nt < 4; ++nt)
                bnxt[nt] = *(const f16x8*)&Wt2[wrow + nt * 2048 + (ks + 1) * 32];
        }
        int kb = ks * 32 + quad * 8;
        f16x8 c0 = *(const f16x8*)&As[(rw * 16 + lm) * LDA + kb];
        #pragma unroll
        for (int nt = 0; nt < 4; ++nt)
            acc[nt] = __builtin_amdgcn_mfma_f32_16x16x32_f16(c0, bcur[nt], acc[nt], 0, 0, 0);
        #pragma unroll
        for (int nt = 0; nt < 4; ++nt) bcur[nt] = bnxt[nt];
    }
    __syncthreads();   // b4: ALL P reads done -> safe to overwrite

    ushort* Cs = (ushort*)As;
    #pragma unroll
    for (int nt = 0; nt < 4; ++nt) {
        int col = cw * 64 + nt * 16 + lm;
        float bv = b2[col];
        #pragma unroll
        for (int r = 0; r < 4; ++r) {
            int row = rw * 16 + quad * 4 + r;
            Cs[row * LDA + col] = (ushort)f2h(fmaxf(acc[nt][r] + bv, 0.f));
        }
    }
    __syncthreads();   // b5: Cs ready

    #pragma unroll
    for (int j = 0; j < 2; ++j) {
        int lin = tid + j * 256;
        int r = lin >> 4;
        int kc = lin & 15;
        int gr = row0 + r;
        if (gr < N_NODES)
            *(uint4*)&C[gr * 128 + kc * 8] = *(const uint4*)&Cs[r * LDA + kc * 8];
    }

    // ---- per-graph + global stats (scr aliases saff/taff; gather is done) ----
    {
        float* scr = saff;
        int c = tid & 127;
        int rbase = (tid >> 7) * 16;
        int curg = sb[rbase];
        float rs = 0.f, rss = 0.f;
        float ts = 0.f, tss = 0.f;
        for (int r = rbase; r < rbase + 16; ++r) {
            int g = sb[r];
            if (g < 0) break;
            if (g != curg) {
                atomicAdd(&gsum[curg * 128 + c], rs);
                atomicAdd(&gssq[curg * 128 + c], rss);
                rs = 0.f; rss = 0.f; curg = g;
            }
            float v = h2f(Cs[r * LDA + c]);
            rs += v; rss += v * v;
            ts += v; tss += v * v;
        }
        if (curg >= 0) {
            atomicAdd(&gsum[curg * 128 + c], rs);
            atomicAdd(&gssq[curg * 128 + c], rss);
        }
        if (tid >= 128) { scr[c] = ts; taff[c] = tss; }
        __syncthreads();   // b6
        if (tid < 128) {
            float* part = bnpart_out + (blockIdx.x & (NPART - 1)) * 256;
            atomicAdd(&part[c], ts + scr[c]);
            atomicAdd(&part[128 + c], tss + taff[c]);
        }
    }
}

// ---------------- combine (BN affine inline; graph sizes from gstart) -------------

__global__ __launch_bounds__(256) void combine(const float* __restrict__ gsum,
                                               const float* __restrict__ bnstat,
                                               const int* __restrict__ gstart,
                                               const float* __restrict__ gamma,
                                               const float* __restrict__ beta,
                                               const float* __restrict__ LW,
                                               const float* __restrict__ LB,
                                               float* __restrict__ out) {
    int gid = blockIdx.x * 256 + threadIdx.x;
    if (gid >= N_GRAPHS * 128) return;
    int g = gid >> 7;
    int d = gid & 127;
    float c = (float)(gstart[g + 1] - gstart[g]);
    float o = c * LB[0];
    const float invN = 1.0f / (float)N_NODES;
    #pragma unroll
    for (int l = 0; l < N_LAYERS; ++l) {
        const float* part = bnstat + l * NPART * 256;
        float sum = 0.f, ssq = 0.f;
        #pragma unroll
        for (int p = 0; p < NPART; ++p) {
            sum += part[p * 256 + d];
            ssq += part[p * 256 + 128 + d];
        }
        float m = sum * invN;
        float var = ssq * invN - m * m;
        float s = gamma[l * 128 + d] * rsqrtf(var + BN_EPS);
        float t = beta[l * 128 + d] - m * s;
        o += LW[l] * (s * gsum[(l * N_GRAPHS + g) * 128 + d] + c * t);
    }
    out[gid] = o;
}

// ---------------- host launcher ----------------

extern "C" void kernel_launch(void* const* d_in, const int* in_sizes, int n_in,
                              void* d_out, int out_size, void* d_ws, size_t ws_size,
                              hipStream_t stream) {
    const float* x      = (const float*)d_in[0];
    const int*   ei     = (const int*)d_in[1];
    const int*   batch  = (const int*)d_in[2];
    const float* ini_w1 = (const float*)d_in[3];
    const float* ini_b1 = (const float*)d_in[4];
    const float* ini_w2 = (const float*)d_in[5];
    const float* ini_b2 = (const float*)d_in[6];
    const float* gw1    = (const float*)d_in[7];
    const float* gb1    = (const float*)d_in[8];
    const float* gw2    = (const float*)d_in[9];
    const float* gb2    = (const float*)d_in[10];
    const float* gamma  = (const float*)d_in[11];
    const float* beta   = (const float*)d_in[12];
    const float* lw     = (const float*)d_in[13];
    const float* lb     = (const float*)d_in[14];
    float* out = (float*)d_out;

    char* p = (char*)d_ws;
    auto carve = [&](size_t bytes) -> char* {
        char* q = p;
        p += (bytes + 255) & ~(size_t)255;
        return q;
    };
    ushort* z0    = (ushort*)carve(sizeof(ushort) * N_NODES * DIM);
    ushort* z1    = (ushort*)carve(sizeof(ushort) * N_NODES * DIM);
    float* bnstat = (float*)carve(sizeof(float) * BN_FLOATS);
    float* gsum   = (float*)carve(sizeof(float) * N_LAYERS * N_GRAPHS * DIM);
    float* gssq   = (float*)carve(sizeof(float) * N_LAYERS * N_GRAPHS * DIM);
    short* wbf    = (short*)carve(sizeof(short) * 10 * 128 * 128);
    int* gstart   = (int*)carve(sizeof(int) * (N_GRAPHS + 1));
    int* cnt      = (int*)carve(sizeof(int) * N_NODES);
    ushort* slot  = (ushort*)carve(sizeof(ushort) * N_NODES * SLOT_CAP);
    int* bcnt     = (int*)carve(sizeof(int) * NBLK_BIN * NBKT);
    uint* bpool   = (uint*)carve(sizeof(uint) * NBKT * NBLK_BIN * BCAP);  // 6.4 MB

    const int* src = ei;
    const int* dst = ei + N_EDGES;

    prep<<<TWB + NBLK_BIN + GSTART_BLOCKS + ZERO_BLOCKS, 256, 0, stream>>>(
        ini_w1, ini_w2, gw1, gw2, wbf, bnstat,
        src, dst, batch, bcnt, bpool, gstart, gsum, gssq);

    ini_fused<<<GBLOCKS + NBKT, 256, 0, stream>>>(
        x, wbf, ini_b1, wbf + 16384, ini_b2, z0,
        bpool, bcnt, cnt, slot);

    ushort* zprev = z0;
    ushort* znext = z1;
    for (int i = 0; i < N_LAYERS; ++i) {
        const float* bp_in = (i == 0) ? nullptr : bnstat + (i - 1) * NPART * 256;
        const float* gptr  = (i == 0) ? gamma : gamma + (i - 1) * DIM;
        const float* bptr  = (i == 0) ? beta : beta + (i - 1) * DIM;
        gin_fused<<<GIN_BLOCKS, 256, 0, stream>>>(
            zprev, cnt, slot, bp_in, gptr, bptr,
            wbf + (2 + i) * 16384, gb1 + i * DIM,
            wbf + (6 + i) * 16384, gb2 + i * DIM, znext, batch,
            gsum + i * N_GRAPHS * DIM, gssq + i * N_GRAPHS * DIM,
            bnstat + i * NPART * 256);
        ushort* tmp = zprev; zprev = znext; znext = tmp;
    }
    combine<<<(N_GRAPHS * 128 + 255) / 256, 256, 0, stream>>>(
        gsum, bnstat, gstart, gamma, beta, lw, lb, out);
}

// Round 14
// 303.383 us; speedup vs baseline: 1.1656x; 1.1656x over previous
//
#include <hip/hip_runtime.h>

#define N_NODES  50000
#define N_EDGES  600000
#define N_GRAPHS 512
#define DIM      128
#define N_FEAT   78
#define N_LAYERS 4
#define BN_EPS   1e-5f
#define SLOT_CAP 64
#define LDA      136
#define NPART    16

#define NBKT     196                          // ceil(50000/256) dst-range buckets
#define NBLK_BIN 128                          // bin blocks (private regions each)
#define BCAP     64                           // per-(block,bucket) cap: mean 24, +8 sigma
#define EDGES_PER_BIN ((N_EDGES + NBLK_BIN - 1) / NBLK_BIN)   // 4688

#define GSTART_BLOCKS 196                     // boundary scan over sorted batch
#define ZERO_BLOCKS 512                       // zero 2 MB of gsum+gssq
#define GBLOCKS ((N_NODES + 63) / 64)         // 782
#define TW_ELEMS (10 * 16384)
#define BN_FLOATS (N_LAYERS * NPART * 256)    // 16384
#define TWB ((TW_ELEMS + BN_FLOATS + 255) / 256)   // 704

typedef __attribute__((ext_vector_type(8))) _Float16 f16x8;
typedef __attribute__((ext_vector_type(4))) float f32x4;

static __device__ __forceinline__ short f2h(float f) {
    _Float16 h = (_Float16)f;
    union { _Float16 h; short s; } u; u.h = h;
    return u.s;
}
static __device__ __forceinline__ float h2f(ushort s) {
    union { ushort s; _Float16 h; } u; u.s = s;
    return (float)u.h;
}

// ---------------- prep: weight transpose + bnstat zero + edge binning + gstart + zero ----

__global__ __launch_bounds__(256) void prep(const float* __restrict__ ini_w1,
                                            const float* __restrict__ ini_w2,
                                            const float* __restrict__ gw1,
                                            const float* __restrict__ gw2,
                                            short* __restrict__ wt,
                                            float* __restrict__ bnstat,
                                            const int* __restrict__ src,
                                            const int* __restrict__ dst,
                                            const int* __restrict__ batch,
                                            int* __restrict__ bcnt,
                                            uint* __restrict__ bpool,
                                            int* __restrict__ gstart,
                                            float* __restrict__ gsum,
                                            float* __restrict__ gssq) {
    __shared__ int lcur[NBKT];
    int tid = threadIdx.x;
    int b = blockIdx.x;
    if (b < TWB) {
        int gid = b * 256 + tid;
        if (gid < TW_ELEMS) {
            int m = gid >> 14;
            int idx = gid & 16383;
            int n = idx >> 7;
            int k = idx & 127;
            const float* s;
            int K = 128;
            if (m == 0) { s = ini_w1; K = N_FEAT; }
            else if (m == 1) s = ini_w2;
            else if (m < 6) s = gw1 + (m - 2) * 16384;
            else s = gw2 + (m - 6) * 16384;
            float v = (k < K) ? s[k * 128 + n] : 0.f;
            wt[m * 16384 + n * 128 + k] = f2h(v);
        } else {
            int bi = gid - TW_ELEMS;
            if (bi < BN_FLOATS) bnstat[bi] = 0.0f;
        }
        return;
    }
    b -= TWB;
    if (b < NBLK_BIN) {
        for (int i = tid; i < NBKT; i += 256) lcur[i] = 0;
        __syncthreads();
        int base = b * EDGES_PER_BIN;
        int lim = min(base + EDGES_PER_BIN, N_EDGES);
        for (int e = base + tid; e < lim; e += 256) {
            int d = dst[e];
            int s = src[e];
            int bk = d >> 8;
            int p = atomicAdd(&lcur[bk], 1);
            if (p < BCAP)
                bpool[(bk * NBLK_BIN + b) * BCAP + p] =
                    ((uint)(d & 255) << 16) | (uint)s;
        }
        __syncthreads();
        for (int i = tid; i < NBKT; i += 256) bcnt[b * NBKT + i] = lcur[i];
        return;
    }
    b -= NBLK_BIN;
    if (b < GSTART_BLOCKS) {
        int n = b * 256 + tid;
        if (n < N_NODES) {
            int g = batch[n];
            int gp = (n == 0) ? -1 : batch[n - 1];
            for (int gg = gp + 1; gg <= g; ++gg) gstart[gg] = n;
            if (n == N_NODES - 1)
                for (int gg = g + 1; gg <= N_GRAPHS; ++gg) gstart[gg] = N_NODES;
        }
        return;
    }
    b -= GSTART_BLOCKS;
    float4 z = make_float4(0.f, 0.f, 0.f, 0.f);
    float* bse = (b < 256) ? gsum : gssq;
    int off = (b & 255) * 1024 + tid * 4;
    *(float4*)&bse[off] = z;
}

// ---------------- fused: initial MLP (blocks < GBLOCKS) + slot build (rest) -------

__global__ __launch_bounds__(256, 4) void ini_fused(const float* __restrict__ x,
                                                    const short* __restrict__ Wt1,
                                                    const float* __restrict__ b1,
                                                    const short* __restrict__ Wt2,
                                                    const float* __restrict__ b2,
                                                    ushort* __restrict__ Cout,
                                                    const uint* __restrict__ bpool,
                                                    const int* __restrict__ bcnt,
                                                    int* __restrict__ cnt,
                                                    ushort* __restrict__ slot) {
    __shared__ short smem[2 * 64 * LDA];   // 34816 B, aliased per block role
    int tid = threadIdx.x;

    if (blockIdx.x >= GBLOCKS) {
        // ---- slot-build part ----
        int bkt = blockIdx.x - GBLOCKS;
        ushort* lslot = (ushort*)smem;                     // 32768 B
        int* lcnt = (int*)((char*)smem + 32768);           // 1024 B
        int* rcnt = (int*)((char*)smem + 33792);           // 512 B
        lcnt[tid] = 0;
        if (tid < NBLK_BIN) rcnt[tid] = min(bcnt[tid * NBKT + bkt], BCAP);
        __syncthreads();
        const uint* pool = bpool + (size_t)bkt * NBLK_BIN * BCAP;
        #pragma unroll 1
        for (int i = tid; i < NBLK_BIN * BCAP; i += 256) {
            int run = i >> 6;
            int pos = i & (BCAP - 1);
            if (pos < rcnt[run]) {
                uint u = pool[i];
                int ls = u >> 16;
                int p = atomicAdd(&lcnt[ls], 1);
                if (p < SLOT_CAP) lslot[ls * SLOT_CAP + p] = (ushort)(u & 0xffffu);
            }
        }
        __syncthreads();
        int node0 = bkt << 8;
        int gn = node0 + tid;
        if (gn < N_NODES) cnt[gn] = lcnt[tid];
        #pragma unroll
        for (int j = 0; j < 8; ++j) {
            int i = tid + j * 256;
            int r = i >> 3;
            int c = i & 7;
            int g = node0 + r;
            if (g < N_NODES)
                *(uint4*)&slot[g * SLOT_CAP + c * 8] = *(const uint4*)&lslot[r * SLOT_CAP + c * 8];
        }
        return;
    }

    // ---- gemm_ini part: C = relu(A@W1+b1)@W2+b2, A fp32 [N,78] ----
    short* As = smem;
    short* Bs = smem + 64 * LDA;
    int row0 = blockIdx.x * 64;
    int wave = tid >> 6;
    int wlane = tid & 63;
    int rw = wave >> 1;
    int cw = wave & 1;
    int lm = wlane & 15;
    int quad = wlane >> 4;
    const int wrow = (cw * 64 + lm) * 128 + quad * 8;

    f16x8 bcur[4], bnxt[4];
    #pragma unroll
    for (int nt = 0; nt < 4; ++nt)
        bcur[nt] = *(const f16x8*)&Wt1[wrow + nt * 2048];

    #pragma unroll
    for (int j = 0; j < 32; ++j) {
        int lin = tid + j * 256;
        int r = lin >> 7;
        int k = lin & 127;
        int gr = row0 + r;
        float v = 0.f;
        if (gr < N_NODES && k < N_FEAT) v = x[gr * N_FEAT + k];
        As[r * LDA + k] = f2h(v);
    }
    __syncthreads();   // As ready

    f32x4 acc[2][4];
    #pragma unroll
    for (int mt = 0; mt < 2; ++mt)
        #pragma unroll
        for (int nt = 0; nt < 4; ++nt)
            acc[mt][nt] = (f32x4){0.f, 0.f, 0.f, 0.f};

    #pragma unroll
    for (int ks = 0; ks < 4; ++ks) {
        if (ks < 3) {
            #pragma unroll
            for (int nt = 0; nt < 4; ++nt)
                bnxt[nt] = *(const f16x8*)&Wt1[wrow + nt * 2048 + (ks + 1) * 32];
        }
        int kb = ks * 32 + quad * 8;
        f16x8 a0 = *(const f16x8*)&As[(rw * 32 + lm) * LDA + kb];
        f16x8 a1 = *(const f16x8*)&As[(rw * 32 + 16 + lm) * LDA + kb];
        #pragma unroll
        for (int nt = 0; nt < 4; ++nt) {
            acc[0][nt] = __builtin_amdgcn_mfma_f32_16x16x32_f16(a0, bcur[nt], acc[0][nt], 0, 0, 0);
            acc[1][nt] = __builtin_amdgcn_mfma_f32_16x16x32_f16(a1, bcur[nt], acc[1][nt], 0, 0, 0);
        }
        #pragma unroll
        for (int nt = 0; nt < 4; ++nt) bcur[nt] = bnxt[nt];
    }

    #pragma unroll
    for (int nt = 0; nt < 4; ++nt) {
        int col = cw * 64 + nt * 16 + lm;
        float bv = b1[col];
        #pragma unroll
        for (int mt = 0; mt < 2; ++mt) {
            #pragma unroll
            for (int r = 0; r < 4; ++r) {
                int row = rw * 32 + mt * 16 + quad * 4 + r;
                Bs[row * LDA + col] = (short)f2h(fmaxf(acc[mt][nt][r] + bv, 0.f));
            }
        }
    }
    #pragma unroll
    for (int nt = 0; nt < 4; ++nt)
        bcur[nt] = *(const f16x8*)&Wt2[wrow + nt * 2048];
    __syncthreads();   // Bs ready

    #pragma unroll
    for (int mt = 0; mt < 2; ++mt)
        #pragma unroll
        for (int nt = 0; nt < 4; ++nt)
            acc[mt][nt] = (f32x4){0.f, 0.f, 0.f, 0.f};
    #pragma unroll
    for (int ks = 0; ks < 4; ++ks) {
        if (ks < 3) {
            #pragma unroll
            for (int nt = 0; nt < 4; ++nt)
                bnxt[nt] = *(const f16x8*)&Wt2[wrow + nt * 2048 + (ks + 1) * 32];
        }
        int kb = ks * 32 + quad * 8;
        f16x8 a0 = *(const f16x8*)&Bs[(rw * 32 + lm) * LDA + kb];
        f16x8 a1 = *(const f16x8*)&Bs[(rw * 32 + 16 + lm) * LDA + kb];
        #pragma unroll
        for (int nt = 0; nt < 4; ++nt) {
            acc[0][nt] = __builtin_amdgcn_mfma_f32_16x16x32_f16(a0, bcur[nt], acc[0][nt], 0, 0, 0);
            acc[1][nt] = __builtin_amdgcn_mfma_f32_16x16x32_f16(a1, bcur[nt], acc[1][nt], 0, 0, 0);
        }
        #pragma unroll
        for (int nt = 0; nt < 4; ++nt) bcur[nt] = bnxt[nt];
    }

    ushort* Cs = (ushort*)As;
    #pragma unroll
    for (int nt = 0; nt < 4; ++nt) {
        int col = cw * 64 + nt * 16 + lm;
        float bv = b2[col];
        #pragma unroll
        for (int mt = 0; mt < 2; ++mt) {
            #pragma unroll
            for (int r = 0; r < 4; ++r) {
                int row = rw * 32 + mt * 16 + quad * 4 + r;
                Cs[row * LDA + col] = (ushort)f2h(acc[mt][nt][r] + bv);
            }
        }
    }
    __syncthreads();   // Cs ready

    #pragma unroll
    for (int j = 0; j < 4; ++j) {
        int lin = tid + j * 256;
        int r = lin >> 4;
        int kc = lin & 15;
        int gr = row0 + r;
        if (gr < N_NODES)
            *(uint4*)&Cout[gr * 128 + kc * 8] = *(const uint4*)&Cs[r * LDA + kc * 8];
    }
}

// ---------------- fused GIN layer: aggregation + BN affine -> 2-layer MLP + stats ----
// R11 base (64-row tile, single-buffer As) + SLOT PRESTAGE: the block's 8 KB slot
// region + cnt are loaded into LDS with one coalesced read before the gather, so
// the per-8-edge batch loses its slot-list global round-trip (2 chained global
// latencies -> LDS + 1 global). Residency is ~3 blocks/CU (grid-limited), so the
// extra 8.5 KB LDS is free (3 x 27.4 KB << 160 KB).

__global__ __launch_bounds__(256, 4) void gin_fused(const ushort* __restrict__ Z,
                                                    const int* __restrict__ cnt,
                                                    const ushort* __restrict__ slot,
                                                    const float* __restrict__ bnpart,
                                                    const float* __restrict__ gamma,
                                                    const float* __restrict__ beta,
                                                    const short* __restrict__ Wt1,
                                                    const float* __restrict__ b1,
                                                    const short* __restrict__ Wt2,
                                                    const float* __restrict__ b2,
                                                    ushort* __restrict__ C,
                                                    const int* __restrict__ batch,
                                                    float* __restrict__ gsum,
                                                    float* __restrict__ gssq,
                                                    float* __restrict__ bnpart_out) {
    __shared__ short As[64 * LDA];            // gather out -> GEMM1 in -> P -> GEMM2 in -> C
    __shared__ ushort sslot[64 * SLOT_CAP];   // 8 KB prestaged neighbor lists
    __shared__ int scnt[64];
    __shared__ float saff[128], taff[128];
    __shared__ int sb[64];
    int tid = threadIdx.x;
    int row0 = blockIdx.x * 64;

    int wave = tid >> 6;
    int wlane = tid & 63;
    int rw = wave >> 1;
    int cw = wave & 1;
    int lm = wlane & 15;
    int quad = wlane >> 4;
    const int wrow = (cw * 64 + lm) * 128 + quad * 8;

    // prestage slot lists (coalesced 8 KB linear read) + counts + affine + batch
    {
        const uint4* sp = (const uint4*)(slot + (size_t)row0 * SLOT_CAP);
        uint4* dp = (uint4*)sslot;
        #pragma unroll
        for (int j = 0; j < 2; ++j) {
            int i = tid + j * 256;                 // 512 x uint4 = 8 KB
            int node = row0 + (i >> 3);
            uint4 v = {0u, 0u, 0u, 0u};
            if (node < N_NODES) v = sp[i];
            dp[i] = v;
        }
    }
    if (tid < 64) {
        int n = row0 + tid;
        scnt[tid] = (n < N_NODES) ? cnt[n] : 0;
        sb[tid] = (n < N_NODES) ? batch[n] : -1;
    }
    if (tid < 128) {
        float s = 1.0f, t = 0.0f;
        if (bnpart) {
            float sum = 0.f, ssq = 0.f;
            #pragma unroll
            for (int p = 0; p < NPART; ++p) {
                sum += bnpart[p * 256 + tid];
                ssq += bnpart[p * 256 + 128 + tid];
            }
            const float invN = 1.0f / (float)N_NODES;
            float m = sum * invN;
            float var = ssq * invN - m * m;
            s = gamma[tid] * rsqrtf(var + BN_EPS);
            t = beta[tid] - m * s;
        }
        saff[tid] = s; taff[tid] = t;
    }
    __syncthreads();   // b0: sslot/scnt/saff/taff/sb ready

    // ---- gather phase: 16 lanes per node, 16 nodes per pass, 4 passes ----
    {
        int lane = tid & 15;
        int nsub = tid >> 4;
        union U { uint4 u; _Float16 h[8]; };
        union I { uint4 u; ushort s[8]; };
        const uint4* z4 = (const uint4*)Z;
        #pragma unroll 1
        for (int pass = 0; pass < 4; ++pass) {
            int r = pass * 16 + nsub;
            int node = row0 + r;
            float v[8];
            float dsc = 1.0f;
            if (node < N_NODES) {
                U zu; zu.u = z4[node * 16 + lane];
                #pragma unroll
                for (int j = 0; j < 8; ++j) v[j] = (float)zu.h[j];
                int dtrue = scnt[r];
                int d = min(dtrue, SLOT_CAP);
                const ushort* sl = sslot + r * SLOT_CAP;
                int e = 0;
                for (; e + 8 <= d; e += 8) {
                    I si; si.u = *(const uint4*)&sl[e];
                    U u[8];
                    #pragma unroll
                    for (int q = 0; q < 8; ++q) u[q].u = z4[(int)si.s[q] * 16 + lane];
                    #pragma unroll
                    for (int j = 0; j < 8; ++j) {
                        float a = ((float)u[0].h[j] + (float)u[1].h[j]) +
                                  ((float)u[2].h[j] + (float)u[3].h[j]);
                        float b = ((float)u[4].h[j] + (float)u[5].h[j]) +
                                  ((float)u[6].h[j] + (float)u[7].h[j]);
                        v[j] += a + b;
                    }
                }
                if (e + 4 <= d) {
                    int s0 = sl[e], s1 = sl[e + 1], s2 = sl[e + 2], s3 = sl[e + 3];
                    U u0, u1, u2, u3;
                    u0.u = z4[s0 * 16 + lane];
                    u1.u = z4[s1 * 16 + lane];
                    u2.u = z4[s2 * 16 + lane];
                    u3.u = z4[s3 * 16 + lane];
                    #pragma unroll
                    for (int j = 0; j < 8; ++j)
                        v[j] += ((float)u0.h[j] + (float)u1.h[j]) +
                                ((float)u2.h[j] + (float)u3.h[j]);
                    e += 4;
                }
                for (; e < d; ++e) {
                    U u; u.u = z4[(int)sl[e] * 16 + lane];
                    #pragma unroll
                    for (int j = 0; j < 8; ++j) v[j] += (float)u.h[j];
                }
                dsc = 1.0f + (float)dtrue;
            } else {
                #pragma unroll
                for (int j = 0; j < 8; ++j) v[j] = 0.f;
                dsc = 0.f;
            }
            #pragma unroll
            for (int j = 0; j < 8; ++j) {
                int dd = lane * 8 + j;
                As[r * LDA + dd] = f2h(saff[dd] * v[j] + dsc * taff[dd]);
            }
        }
    }

    f16x8 bcur[4], bnxt[4];
    #pragma unroll
    for (int nt = 0; nt < 4; ++nt)
        bcur[nt] = *(const f16x8*)&Wt1[wrow + nt * 2048];
    __syncthreads();   // b1: As (aggregated A) ready

    // ---- GEMM 1: acc = As @ W1 (full accumulation in registers) ----
    f32x4 acc[2][4];
    #pragma unroll
    for (int mt = 0; mt < 2; ++mt)
        #pragma unroll
        for (int nt = 0; nt < 4; ++nt)
            acc[mt][nt] = (f32x4){0.f, 0.f, 0.f, 0.f};
    #pragma unroll
    for (int ks = 0; ks < 4; ++ks) {
        if (ks < 3) {
            #pragma unroll
            for (int nt = 0; nt < 4; ++nt)
                bnxt[nt] = *(const f16x8*)&Wt1[wrow + nt * 2048 + (ks + 1) * 32];
        }
        int kb = ks * 32 + quad * 8;
        f16x8 a0 = *(const f16x8*)&As[(rw * 32 + lm) * LDA + kb];
        f16x8 a1 = *(const f16x8*)&As[(rw * 32 + 16 + lm) * LDA + kb];
        #pragma unroll
        for (int nt = 0; nt < 4; ++nt) {
            acc[0][nt] = __builtin_amdgcn_mfma_f32_16x16x32_f16(a0, bcur[nt], acc[0][nt], 0, 0, 0);
            acc[1][nt] = __builtin_amdgcn_mfma_f32_16x16x32_f16(a1, bcur[nt], acc[1][nt], 0, 0, 0);
        }
        #pragma unroll
        for (int nt = 0; nt < 4; ++nt) bcur[nt] = bnxt[nt];
    }
    #pragma unroll
    for (int nt = 0; nt < 4; ++nt)
        bcur[nt] = *(const f16x8*)&Wt2[wrow + nt * 2048];
    __syncthreads();   // b2: ALL As reads done -> safe to overwrite in place

    // P = relu(acc + b1) -> As
    #pragma unroll
    for (int nt = 0; nt < 4; ++nt) {
        int col = cw * 64 + nt * 16 + lm;
        float bv = b1[col];
        #pragma unroll
        for (int mt = 0; mt < 2; ++mt) {
            #pragma unroll
            for (int r = 0; r < 4; ++r) {
                int row = rw * 32 + mt * 16 + quad * 4 + r;
                As[row * LDA + col] = (short)f2h(fmaxf(acc[mt][nt][r] + bv, 0.f));
            }
        }
    }
    __syncthreads();   // b3: P ready

    // ---- GEMM 2: acc = P @ W2 ----
    #pragma unroll
    for (int mt = 0; mt < 2; ++mt)
        #pragma unroll
        for (int nt = 0; nt < 4; ++nt)
            acc[mt][nt] = (f32x4){0.f, 0.f, 0.f, 0.f};
    #pragma unroll
    for (int ks = 0; ks < 4; ++ks) {
        if (ks < 3) {
            #pragma unroll
            for (int nt = 0; nt < 4; ++nt)
                bnxt[nt] = *(const f16x8*)&Wt2[wrow + nt * 2048 + (ks + 1) * 32];
        }
        int kb = ks * 32 + quad * 8;
        f16x8 c0 = *(const f16x8*)&As[(rw * 32 + lm) * LDA + kb];
        f16x8 c1 = *(const f16x8*)&As[(rw * 32 + 16 + lm) * LDA + kb];
        #pragma unroll
        for (int nt = 0; nt < 4; ++nt) {
            acc[0][nt] = __builtin_amdgcn_mfma_f32_16x16x32_f16(c0, bcur[nt], acc[0][nt], 0, 0, 0);
            acc[1][nt] = __builtin_amdgcn_mfma_f32_16x16x32_f16(c1, bcur[nt], acc[1][nt], 0, 0, 0);
        }
        #pragma unroll
        for (int nt = 0; nt < 4; ++nt) bcur[nt] = bnxt[nt];
    }
    __syncthreads();   // b4: ALL P reads done -> safe to overwrite

    ushort* Cs = (ushort*)As;
    #pragma unroll
    for (int nt = 0; nt < 4; ++nt) {
        int col = cw * 64 + nt * 16 + lm;
        float bv = b2[col];
        #pragma unroll
        for (int mt = 0; mt < 2; ++mt) {
            #pragma unroll
            for (int r = 0; r < 4; ++r) {
                int row = rw * 32 + mt * 16 + quad * 4 + r;
                Cs[row * LDA + col] = (ushort)f2h(fmaxf(acc[mt][nt][r] + bv, 0.f));
            }
        }
    }
    __syncthreads();   // b5: Cs ready

    #pragma unroll
    for (int j = 0; j < 4; ++j) {
        int lin = tid + j * 256;
        int r = lin >> 4;
        int kc = lin & 15;
        int gr = row0 + r;
        if (gr < N_NODES)
            *(uint4*)&C[gr * 128 + kc * 8] = *(const uint4*)&Cs[r * LDA + kc * 8];
    }

    // ---- per-graph + global stats (scr aliases saff/taff; gather is done) ----
    {
        float* scr = saff;
        int c = tid & 127;
        int rbase = (tid >> 7) * 32;
        int curg = sb[rbase];
        float rs = 0.f, rss = 0.f;
        float ts = 0.f, tss = 0.f;
        for (int r = rbase; r < rbase + 32; ++r) {
            int g = sb[r];
            if (g < 0) break;
            if (g != curg) {
                atomicAdd(&gsum[curg * 128 + c], rs);
                atomicAdd(&gssq[curg * 128 + c], rss);
                rs = 0.f; rss = 0.f; curg = g;
            }
            float v = h2f(Cs[r * LDA + c]);
            rs += v; rss += v * v;
            ts += v; tss += v * v;
        }
        if (curg >= 0) {
            atomicAdd(&gsum[curg * 128 + c], rs);
            atomicAdd(&gssq[curg * 128 + c], rss);
        }
        if (tid >= 128) { scr[c] = ts; taff[c] = tss; }
        __syncthreads();   // b6
        if (tid < 128) {
            float* part = bnpart_out + (blockIdx.x & (NPART - 1)) * 256;
            atomicAdd(&part[c], ts + scr[c]);
            atomicAdd(&part[128 + c], tss + taff[c]);
        }
    }
}

// ---------------- combine (BN affine inline; graph sizes from gstart) -------------

__global__ __launch_bounds__(256) void combine(const float* __restrict__ gsum,
                                               const float* __restrict__ bnstat,
                                               const int* __restrict__ gstart,
                                               const float* __restrict__ gamma,
                                               const float* __restrict__ beta,
                                               const float* __restrict__ LW,
                                               const float* __restrict__ LB,
                                               float* __restrict__ out) {
    int gid = blockIdx.x * 256 + threadIdx.x;
    if (gid >= N_GRAPHS * 128) return;
    int g = gid >> 7;
    int d = gid & 127;
    float c = (float)(gstart[g + 1] - gstart[g]);
    float o = c * LB[0];
    const float invN = 1.0f / (float)N_NODES;
    #pragma unroll
    for (int l = 0; l < N_LAYERS; ++l) {
        const float* part = bnstat + l * NPART * 256;
        float sum = 0.f, ssq = 0.f;
        #pragma unroll
        for (int p = 0; p < NPART; ++p) {
            sum += part[p * 256 + d];
            ssq += part[p * 256 + 128 + d];
        }
        float m = sum * invN;
        float var = ssq * invN - m * m;
        float s = gamma[l * 128 + d] * rsqrtf(var + BN_EPS);
        float t = beta[l * 128 + d] - m * s;
        o += LW[l] * (s * gsum[(l * N_GRAPHS + g) * 128 + d] + c * t);
    }
    out[gid] = o;
}

// ---------------- host launcher ----------------

extern "C" void kernel_launch(void* const* d_in, const int* in_sizes, int n_in,
                              void* d_out, int out_size, void* d_ws, size_t ws_size,
                              hipStream_t stream) {
    const float* x      = (const float*)d_in[0];
    const int*   ei     = (const int*)d_in[1];
    const int*   batch  = (const int*)d_in[2];
    const float* ini_w1 = (const float*)d_in[3];
    const float* ini_b1 = (const float*)d_in[4];
    const float* ini_w2 = (const float*)d_in[5];
    const float* ini_b2 = (const float*)d_in[6];
    const float* gw1    = (const float*)d_in[7];
    const float* gb1    = (const float*)d_in[8];
    const float* gw2    = (const float*)d_in[9];
    const float* gb2    = (const float*)d_in[10];
    const float* gamma  = (const float*)d_in[11];
    const float* beta   = (const float*)d_in[12];
    const float* lw     = (const float*)d_in[13];
    const float* lb     = (const float*)d_in[14];
    float* out = (float*)d_out;

    char* p = (char*)d_ws;
    auto carve = [&](size_t bytes) -> char* {
        char* q = p;
        p += (bytes + 255) & ~(size_t)255;
        return q;
    };
    ushort* z0    = (ushort*)carve(sizeof(ushort) * N_NODES * DIM);
    ushort* z1    = (ushort*)carve(sizeof(ushort) * N_NODES * DIM);
    float* bnstat = (float*)carve(sizeof(float) * BN_FLOATS);
    float* gsum   = (float*)carve(sizeof(float) * N_LAYERS * N_GRAPHS * DIM);
    float* gssq   = (float*)carve(sizeof(float) * N_LAYERS * N_GRAPHS * DIM);
    short* wbf    = (short*)carve(sizeof(short) * 10 * 128 * 128);
    int* gstart   = (int*)carve(sizeof(int) * (N_GRAPHS + 1));
    int* cnt      = (int*)carve(sizeof(int) * N_NODES);
    ushort* slot  = (ushort*)carve(sizeof(ushort) * (N_NODES + 64) * SLOT_CAP);
    int* bcnt     = (int*)carve(sizeof(int) * NBLK_BIN * NBKT);
    uint* bpool   = (uint*)carve(sizeof(uint) * NBKT * NBLK_BIN * BCAP);  // 6.4 MB

    const int* src = ei;
    const int* dst = ei + N_EDGES;

    prep<<<TWB + NBLK_BIN + GSTART_BLOCKS + ZERO_BLOCKS, 256, 0, stream>>>(
        ini_w1, ini_w2, gw1, gw2, wbf, bnstat,
        src, dst, batch, bcnt, bpool, gstart, gsum, gssq);

    ini_fused<<<GBLOCKS + NBKT, 256, 0, stream>>>(
        x, wbf, ini_b1, wbf + 16384, ini_b2, z0,
        bpool, bcnt, cnt, slot);

    ushort* zprev = z0;
    ushort* znext = z1;
    for (int i = 0; i < N_LAYERS; ++i) {
        const float* bp_in = (i == 0) ? nullptr : bnstat + (i - 1) * NPART * 256;
        const float* gptr  = (i == 0) ? gamma : gamma + (i - 1) * DIM;
        const float* bptr  = (i == 0) ? beta : beta + (i - 1) * DIM;
        gin_fused<<<GBLOCKS, 256, 0, stream>>>(
            zprev, cnt, slot, bp_in, gptr, bptr,
            wbf + (2 + i) * 16384, gb1 + i * DIM,
            wbf + (6 + i) * 16384, gb2 + i * DIM, znext, batch,
            gsum + i * N_GRAPHS * DIM, gssq + i * N_GRAPHS * DIM,
            bnstat + i * NPART * 256);
        ushort* tmp = zprev; zprev = znext; znext = tmp;
    }
    combine<<<(N_GRAPHS * 128 + 255) / 256, 256, 0, stream>>>(
        gsum, bnstat, gstart, gamma, beta, lw, lb, out);
}

// Round 15
// 296.189 us; speedup vs baseline: 1.1939x; 1.0243x over previous
//
#include <hip/hip_runtime.h>

#define N_NODES  50000
#define N_EDGES  600000
#define N_GRAPHS 512
#define DIM      128
#define N_FEAT   78
#define N_LAYERS 4
#define BN_EPS   1e-5f
#define SLOT_CAP 64
#define LDA      136
#define NPART    16

#define NBKT     196                          // ceil(50000/256) dst-range buckets
#define NBLK_BIN 128                          // bin blocks (private regions each)
#define BCAP     64                           // per-(block,bucket) cap: mean 24, +8 sigma
#define EDGES_PER_BIN ((N_EDGES + NBLK_BIN - 1) / NBLK_BIN)   // 4688

#define GSTART_BLOCKS 196                     // boundary scan over sorted batch
#define ZERO_BLOCKS 512                       // zero 2 MB of gsum+gssq
#define GBLOCKS ((N_NODES + 63) / 64)         // 782
#define TW_ELEMS (10 * 16384)
#define BN_FLOATS (N_LAYERS * NPART * 256)    // 16384
#define TWB ((TW_ELEMS + BN_FLOATS + 255) / 256)   // 704

typedef __attribute__((ext_vector_type(8))) _Float16 f16x8;
typedef __attribute__((ext_vector_type(4))) float f32x4;

static __device__ __forceinline__ short f2h(float f) {
    _Float16 h = (_Float16)f;
    union { _Float16 h; short s; } u; u.h = h;
    return u.s;
}
static __device__ __forceinline__ float h2f(ushort s) {
    union { ushort s; _Float16 h; } u; u.s = s;
    return (float)u.h;
}

// ---------------- prep: weight transpose + bnstat zero + edge binning + gstart + zero ----

__global__ __launch_bounds__(256) void prep(const float* __restrict__ ini_w1,
                                            const float* __restrict__ ini_w2,
                                            const float* __restrict__ gw1,
                                            const float* __restrict__ gw2,
                                            short* __restrict__ wt,
                                            float* __restrict__ bnstat,
                                            const int* __restrict__ src,
                                            const int* __restrict__ dst,
                                            const int* __restrict__ batch,
                                            int* __restrict__ bcnt,
                                            uint* __restrict__ bpool,
                                            int* __restrict__ gstart,
                                            float* __restrict__ gsum,
                                            float* __restrict__ gssq) {
    __shared__ int lcur[NBKT];
    int tid = threadIdx.x;
    int b = blockIdx.x;
    if (b < TWB) {
        int gid = b * 256 + tid;
        if (gid < TW_ELEMS) {
            int m = gid >> 14;
            int idx = gid & 16383;
            int n = idx >> 7;
            int k = idx & 127;
            const float* s;
            int K = 128;
            if (m == 0) { s = ini_w1; K = N_FEAT; }
            else if (m == 1) s = ini_w2;
            else if (m < 6) s = gw1 + (m - 2) * 16384;
            else s = gw2 + (m - 6) * 16384;
            float v = (k < K) ? s[k * 128 + n] : 0.f;
            wt[m * 16384 + n * 128 + k] = f2h(v);
        } else {
            int bi = gid - TW_ELEMS;
            if (bi < BN_FLOATS) bnstat[bi] = 0.0f;
        }
        return;
    }
    b -= TWB;
    if (b < NBLK_BIN) {
        for (int i = tid; i < NBKT; i += 256) lcur[i] = 0;
        __syncthreads();
        int base = b * EDGES_PER_BIN;
        int lim = min(base + EDGES_PER_BIN, N_EDGES);
        for (int e = base + tid; e < lim; e += 256) {
            int d = dst[e];
            int s = src[e];
            int bk = d >> 8;
            int p = atomicAdd(&lcur[bk], 1);
            if (p < BCAP)
                bpool[(bk * NBLK_BIN + b) * BCAP + p] =
                    ((uint)(d & 255) << 16) | (uint)s;
        }
        __syncthreads();
        for (int i = tid; i < NBKT; i += 256) bcnt[b * NBKT + i] = lcur[i];
        return;
    }
    b -= NBLK_BIN;
    if (b < GSTART_BLOCKS) {
        int n = b * 256 + tid;
        if (n < N_NODES) {
            int g = batch[n];
            int gp = (n == 0) ? -1 : batch[n - 1];
            for (int gg = gp + 1; gg <= g; ++gg) gstart[gg] = n;
            if (n == N_NODES - 1)
                for (int gg = g + 1; gg <= N_GRAPHS; ++gg) gstart[gg] = N_NODES;
        }
        return;
    }
    b -= GSTART_BLOCKS;
    float4 z = make_float4(0.f, 0.f, 0.f, 0.f);
    float* bse = (b < 256) ? gsum : gssq;
    int off = (b & 255) * 1024 + tid * 4;
    *(float4*)&bse[off] = z;
}

// ---------------- fused: initial MLP (blocks < GBLOCKS) + slot build (rest) -------

__global__ __launch_bounds__(256, 4) void ini_fused(const float* __restrict__ x,
                                                    const short* __restrict__ Wt1,
                                                    const float* __restrict__ b1,
                                                    const short* __restrict__ Wt2,
                                                    const float* __restrict__ b2,
                                                    ushort* __restrict__ Cout,
                                                    const uint* __restrict__ bpool,
                                                    const int* __restrict__ bcnt,
                                                    int* __restrict__ cnt,
                                                    ushort* __restrict__ slot) {
    __shared__ short smem[2 * 64 * LDA];   // 34816 B, aliased per block role
    int tid = threadIdx.x;

    if (blockIdx.x >= GBLOCKS) {
        // ---- slot-build part ----
        int bkt = blockIdx.x - GBLOCKS;
        ushort* lslot = (ushort*)smem;                     // 32768 B
        int* lcnt = (int*)((char*)smem + 32768);           // 1024 B
        int* rcnt = (int*)((char*)smem + 33792);           // 512 B
        lcnt[tid] = 0;
        if (tid < NBLK_BIN) rcnt[tid] = min(bcnt[tid * NBKT + bkt], BCAP);
        __syncthreads();
        const uint* pool = bpool + (size_t)bkt * NBLK_BIN * BCAP;
        #pragma unroll 1
        for (int i = tid; i < NBLK_BIN * BCAP; i += 256) {
            int run = i >> 6;
            int pos = i & (BCAP - 1);
            if (pos < rcnt[run]) {
                uint u = pool[i];
                int ls = u >> 16;
                int p = atomicAdd(&lcnt[ls], 1);
                if (p < SLOT_CAP) lslot[ls * SLOT_CAP + p] = (ushort)(u & 0xffffu);
            }
        }
        __syncthreads();
        int node0 = bkt << 8;
        int gn = node0 + tid;
        if (gn < N_NODES) cnt[gn] = lcnt[tid];
        #pragma unroll
        for (int j = 0; j < 8; ++j) {
            int i = tid + j * 256;
            int r = i >> 3;
            int c = i & 7;
            int g = node0 + r;
            if (g < N_NODES)
                *(uint4*)&slot[g * SLOT_CAP + c * 8] = *(const uint4*)&lslot[r * SLOT_CAP + c * 8];
        }
        return;
    }

    // ---- gemm_ini part: C = relu(A@W1+b1)@W2+b2, A fp32 [N,78] ----
    short* As = smem;
    short* Bs = smem + 64 * LDA;
    int row0 = blockIdx.x * 64;
    int wave = tid >> 6;
    int wlane = tid & 63;
    int rw = wave >> 1;
    int cw = wave & 1;
    int lm = wlane & 15;
    int quad = wlane >> 4;
    const int wrow = (cw * 64 + lm) * 128 + quad * 8;

    f16x8 bcur[4], bnxt[4];
    #pragma unroll
    for (int nt = 0; nt < 4; ++nt)
        bcur[nt] = *(const f16x8*)&Wt1[wrow + nt * 2048];

    #pragma unroll
    for (int j = 0; j < 32; ++j) {
        int lin = tid + j * 256;
        int r = lin >> 7;
        int k = lin & 127;
        int gr = row0 + r;
        float v = 0.f;
        if (gr < N_NODES && k < N_FEAT) v = x[gr * N_FEAT + k];
        As[r * LDA + k] = f2h(v);
    }
    __syncthreads();   // As ready

    f32x4 acc[2][4];
    #pragma unroll
    for (int mt = 0; mt < 2; ++mt)
        #pragma unroll
        for (int nt = 0; nt < 4; ++nt)
            acc[mt][nt] = (f32x4){0.f, 0.f, 0.f, 0.f};

    #pragma unroll
    for (int ks = 0; ks < 4; ++ks) {
        if (ks < 3) {
            #pragma unroll
            for (int nt = 0; nt < 4; ++nt)
                bnxt[nt] = *(const f16x8*)&Wt1[wrow + nt * 2048 + (ks + 1) * 32];
        }
        int kb = ks * 32 + quad * 8;
        f16x8 a0 = *(const f16x8*)&As[(rw * 32 + lm) * LDA + kb];
        f16x8 a1 = *(const f16x8*)&As[(rw * 32 + 16 + lm) * LDA + kb];
        #pragma unroll
        for (int nt = 0; nt < 4; ++nt) {
            acc[0][nt] = __builtin_amdgcn_mfma_f32_16x16x32_f16(a0, bcur[nt], acc[0][nt], 0, 0, 0);
            acc[1][nt] = __builtin_amdgcn_mfma_f32_16x16x32_f16(a1, bcur[nt], acc[1][nt], 0, 0, 0);
        }
        #pragma unroll
        for (int nt = 0; nt < 4; ++nt) bcur[nt] = bnxt[nt];
    }

    #pragma unroll
    for (int nt = 0; nt < 4; ++nt) {
        int col = cw * 64 + nt * 16 + lm;
        float bv = b1[col];
        #pragma unroll
        for (int mt = 0; mt < 2; ++mt) {
            #pragma unroll
            for (int r = 0; r < 4; ++r) {
                int row = rw * 32 + mt * 16 + quad * 4 + r;
                Bs[row * LDA + col] = (short)f2h(fmaxf(acc[mt][nt][r] + bv, 0.f));
            }
        }
    }
    #pragma unroll
    for (int nt = 0; nt < 4; ++nt)
        bcur[nt] = *(const f16x8*)&Wt2[wrow + nt * 2048];
    __syncthreads();   // Bs ready

    #pragma unroll
    for (int mt = 0; mt < 2; ++mt)
        #pragma unroll
        for (int nt = 0; nt < 4; ++nt)
            acc[mt][nt] = (f32x4){0.f, 0.f, 0.f, 0.f};
    #pragma unroll
    for (int ks = 0; ks < 4; ++ks) {
        if (ks < 3) {
            #pragma unroll
            for (int nt = 0; nt < 4; ++nt)
                bnxt[nt] = *(const f16x8*)&Wt2[wrow + nt * 2048 + (ks + 1) * 32];
        }
        int kb = ks * 32 + quad * 8;
        f16x8 a0 = *(const f16x8*)&Bs[(rw * 32 + lm) * LDA + kb];
        f16x8 a1 = *(const f16x8*)&Bs[(rw * 32 + 16 + lm) * LDA + kb];
        #pragma unroll
        for (int nt = 0; nt < 4; ++nt) {
            acc[0][nt] = __builtin_amdgcn_mfma_f32_16x16x32_f16(a0, bcur[nt], acc[0][nt], 0, 0, 0);
            acc[1][nt] = __builtin_amdgcn_mfma_f32_16x16x32_f16(a1, bcur[nt], acc[1][nt], 0, 0, 0);
        }
        #pragma unroll
        for (int nt = 0; nt < 4; ++nt) bcur[nt] = bnxt[nt];
    }

    ushort* Cs = (ushort*)As;
    #pragma unroll
    for (int nt = 0; nt < 4; ++nt) {
        int col = cw * 64 + nt * 16 + lm;
        float bv = b2[col];
        #pragma unroll
        for (int mt = 0; mt < 2; ++mt) {
            #pragma unroll
            for (int r = 0; r < 4; ++r) {
                int row = rw * 32 + mt * 16 + quad * 4 + r;
                Cs[row * LDA + col] = (ushort)f2h(acc[mt][nt][r] + bv);
            }
        }
    }
    __syncthreads();   // Cs ready

    #pragma unroll
    for (int j = 0; j < 4; ++j) {
        int lin = tid + j * 256;
        int r = lin >> 4;
        int kc = lin & 15;
        int gr = row0 + r;
        if (gr < N_NODES)
            *(uint4*)&Cout[gr * 128 + kc * 8] = *(const uint4*)&Cs[r * LDA + kc * 8];
    }
}

// ---------------- fused GIN layer: aggregation + BN affine -> 2-layer MLP + stats ----
// R13 base (slot prestage in LDS) + 16-WIDE PREDICATED GATHER BATCH: with mean
// degree 12, the old ceil(d/8) loop paid 2 serial global-latency rounds per node;
// one 16-wide zero-filled batch (u[q] = q<rem ? load : 0, rem uniform per 16-lane
// node group) collapses the typical node to ONE round of 16 concurrent row loads.
// Peak VGPR ~100 (u[16] staging), under the (256,4) cap of 128 -> no spill.

__global__ __launch_bounds__(256, 4) void gin_fused(const ushort* __restrict__ Z,
                                                    const int* __restrict__ cnt,
                                                    const ushort* __restrict__ slot,
                                                    const float* __restrict__ bnpart,
                                                    const float* __restrict__ gamma,
                                                    const float* __restrict__ beta,
                                                    const short* __restrict__ Wt1,
                                                    const float* __restrict__ b1,
                                                    const short* __restrict__ Wt2,
                                                    const float* __restrict__ b2,
                                                    ushort* __restrict__ C,
                                                    const int* __restrict__ batch,
                                                    float* __restrict__ gsum,
                                                    float* __restrict__ gssq,
                                                    float* __restrict__ bnpart_out) {
    __shared__ short As[64 * LDA];            // gather out -> GEMM1 in -> P -> GEMM2 in -> C
    __shared__ ushort sslot[64 * SLOT_CAP];   // 8 KB prestaged neighbor lists
    __shared__ int scnt[64];
    __shared__ float saff[128], taff[128];
    __shared__ int sb[64];
    int tid = threadIdx.x;
    int row0 = blockIdx.x * 64;

    int wave = tid >> 6;
    int wlane = tid & 63;
    int rw = wave >> 1;
    int cw = wave & 1;
    int lm = wlane & 15;
    int quad = wlane >> 4;
    const int wrow = (cw * 64 + lm) * 128 + quad * 8;

    // prestage slot lists (coalesced 8 KB linear read) + counts + affine + batch
    {
        const uint4* sp = (const uint4*)(slot + (size_t)row0 * SLOT_CAP);
        uint4* dp = (uint4*)sslot;
        #pragma unroll
        for (int j = 0; j < 2; ++j) {
            int i = tid + j * 256;                 // 512 x uint4 = 8 KB
            int node = row0 + (i >> 3);
            uint4 v = {0u, 0u, 0u, 0u};
            if (node < N_NODES) v = sp[i];
            dp[i] = v;
        }
    }
    if (tid < 64) {
        int n = row0 + tid;
        scnt[tid] = (n < N_NODES) ? cnt[n] : 0;
        sb[tid] = (n < N_NODES) ? batch[n] : -1;
    }
    if (tid < 128) {
        float s = 1.0f, t = 0.0f;
        if (bnpart) {
            float sum = 0.f, ssq = 0.f;
            #pragma unroll
            for (int p = 0; p < NPART; ++p) {
                sum += bnpart[p * 256 + tid];
                ssq += bnpart[p * 256 + 128 + tid];
            }
            const float invN = 1.0f / (float)N_NODES;
            float m = sum * invN;
            float var = ssq * invN - m * m;
            s = gamma[tid] * rsqrtf(var + BN_EPS);
            t = beta[tid] - m * s;
        }
        saff[tid] = s; taff[tid] = t;
    }
    __syncthreads();   // b0: sslot/scnt/saff/taff/sb ready

    // ---- gather phase: 16 lanes per node, 16 nodes per pass, 4 passes ----
    {
        int lane = tid & 15;
        int nsub = tid >> 4;
        union U { uint4 u; _Float16 h[8]; };
        union I { uint4 u; ushort s[8]; };
        const uint4* z4 = (const uint4*)Z;
        #pragma unroll 1
        for (int pass = 0; pass < 4; ++pass) {
            int r = pass * 16 + nsub;
            int node = row0 + r;
            float v[8];
            float dsc = 1.0f;
            if (node < N_NODES) {
                U zu; zu.u = z4[node * 16 + lane];
                #pragma unroll
                for (int j = 0; j < 8; ++j) v[j] = (float)zu.h[j];
                int dtrue = scnt[r];
                int d = min(dtrue, SLOT_CAP);
                const ushort* sl = sslot + r * SLOT_CAP;
                #pragma unroll 1
                for (int e = 0; e < d; e += 16) {
                    I si0, si1;
                    si0.u = *(const uint4*)&sl[e];       // entries e..e+7
                    si1.u = *(const uint4*)&sl[e + 8];   // entries e+8..e+15 (in-bounds LDS; masked below)
                    int rem = d - e;
                    U u[16];
                    #pragma unroll
                    for (int q = 0; q < 8; ++q) {
                        uint4 t = {0u, 0u, 0u, 0u};
                        if (q < rem) t = z4[(int)si0.s[q] * 16 + lane];
                        u[q].u = t;
                    }
                    #pragma unroll
                    for (int q = 0; q < 8; ++q) {
                        uint4 t = {0u, 0u, 0u, 0u};
                        if (q + 8 < rem) t = z4[(int)si1.s[q] * 16 + lane];
                        u[q + 8].u = t;
                    }
                    #pragma unroll
                    for (int j = 0; j < 8; ++j) {
                        float a = ((float)u[0].h[j] + (float)u[1].h[j]) +
                                  ((float)u[2].h[j] + (float)u[3].h[j]);
                        float b = ((float)u[4].h[j] + (float)u[5].h[j]) +
                                  ((float)u[6].h[j] + (float)u[7].h[j]);
                        float c = ((float)u[8].h[j] + (float)u[9].h[j]) +
                                  ((float)u[10].h[j] + (float)u[11].h[j]);
                        float dd = ((float)u[12].h[j] + (float)u[13].h[j]) +
                                   ((float)u[14].h[j] + (float)u[15].h[j]);
                        v[j] += (a + b) + (c + dd);
                    }
                }
                dsc = 1.0f + (float)dtrue;
            } else {
                #pragma unroll
                for (int j = 0; j < 8; ++j) v[j] = 0.f;
                dsc = 0.f;
            }
            #pragma unroll
            for (int j = 0; j < 8; ++j) {
                int dd = lane * 8 + j;
                As[r * LDA + dd] = f2h(saff[dd] * v[j] + dsc * taff[dd]);
            }
        }
    }

    f16x8 bcur[4], bnxt[4];
    #pragma unroll
    for (int nt = 0; nt < 4; ++nt)
        bcur[nt] = *(const f16x8*)&Wt1[wrow + nt * 2048];
    __syncthreads();   // b1: As (aggregated A) ready

    // ---- GEMM 1: acc = As @ W1 (full accumulation in registers) ----
    f32x4 acc[2][4];
    #pragma unroll
    for (int mt = 0; mt < 2; ++mt)
        #pragma unroll
        for (int nt = 0; nt < 4; ++nt)
            acc[mt][nt] = (f32x4){0.f, 0.f, 0.f, 0.f};
    #pragma unroll
    for (int ks = 0; ks < 4; ++ks) {
        if (ks < 3) {
            #pragma unroll
            for (int nt = 0; nt < 4; ++nt)
                bnxt[nt] = *(const f16x8*)&Wt1[wrow + nt * 2048 + (ks + 1) * 32];
        }
        int kb = ks * 32 + quad * 8;
        f16x8 a0 = *(const f16x8*)&As[(rw * 32 + lm) * LDA + kb];
        f16x8 a1 = *(const f16x8*)&As[(rw * 32 + 16 + lm) * LDA + kb];
        #pragma unroll
        for (int nt = 0; nt < 4; ++nt) {
            acc[0][nt] = __builtin_amdgcn_mfma_f32_16x16x32_f16(a0, bcur[nt], acc[0][nt], 0, 0, 0);
            acc[1][nt] = __builtin_amdgcn_mfma_f32_16x16x32_f16(a1, bcur[nt], acc[1][nt], 0, 0, 0);
        }
        #pragma unroll
        for (int nt = 0; nt < 4; ++nt) bcur[nt] = bnxt[nt];
    }
    #pragma unroll
    for (int nt = 0; nt < 4; ++nt)
        bcur[nt] = *(const f16x8*)&Wt2[wrow + nt * 2048];
    __syncthreads();   // b2: ALL As reads done -> safe to overwrite in place

    // P = relu(acc + b1) -> As
    #pragma unroll
    for (int nt = 0; nt < 4; ++nt) {
        int col = cw * 64 + nt * 16 + lm;
        float bv = b1[col];
        #pragma unroll
        for (int mt = 0; mt < 2; ++mt) {
            #pragma unroll
            for (int r = 0; r < 4; ++r) {
                int row = rw * 32 + mt * 16 + quad * 4 + r;
                As[row * LDA + col] = (short)f2h(fmaxf(acc[mt][nt][r] + bv, 0.f));
            }
        }
    }
    __syncthreads();   // b3: P ready

    // ---- GEMM 2: acc = P @ W2 ----
    #pragma unroll
    for (int mt = 0; mt < 2; ++mt)
        #pragma unroll
        for (int nt = 0; nt < 4; ++nt)
            acc[mt][nt] = (f32x4){0.f, 0.f, 0.f, 0.f};
    #pragma unroll
    for (int ks = 0; ks < 4; ++ks) {
        if (ks < 3) {
            #pragma unroll
            for (int nt = 0; nt < 4; ++nt)
                bnxt[nt] = *(const f16x8*)&Wt2[wrow + nt * 2048 + (ks + 1) * 32];
        }
        int kb = ks * 32 + quad * 8;
        f16x8 c0 = *(const f16x8*)&As[(rw * 32 + lm) * LDA + kb];
        f16x8 c1 = *(const f16x8*)&As[(rw * 32 + 16 + lm) * LDA + kb];
        #pragma unroll
        for (int nt = 0; nt < 4; ++nt) {
            acc[0][nt] = __builtin_amdgcn_mfma_f32_16x16x32_f16(c0, bcur[nt], acc[0][nt], 0, 0, 0);
            acc[1][nt] = __builtin_amdgcn_mfma_f32_16x16x32_f16(c1, bcur[nt], acc[1][nt], 0, 0, 0);
        }
        #pragma unroll
        for (int nt = 0; nt < 4; ++nt) bcur[nt] = bnxt[nt];
    }
    __syncthreads();   // b4: ALL P reads done -> safe to overwrite

    ushort* Cs = (ushort*)As;
    #pragma unroll
    for (int nt = 0; nt < 4; ++nt) {
        int col = cw * 64 + nt * 16 + lm;
        float bv = b2[col];
        #pragma unroll
        for (int mt = 0; mt < 2; ++mt) {
            #pragma unroll
            for (int r = 0; r < 4; ++r) {
                int row = rw * 32 + mt * 16 + quad * 4 + r;
                Cs[row * LDA + col] = (ushort)f2h(fmaxf(acc[mt][nt][r] + bv, 0.f));
            }
        }
    }
    __syncthreads();   // b5: Cs ready

    #pragma unroll
    for (int j = 0; j < 4; ++j) {
        int lin = tid + j * 256;
        int r = lin >> 4;
        int kc = lin & 15;
        int gr = row0 + r;
        if (gr < N_NODES)
            *(uint4*)&C[gr * 128 + kc * 8] = *(const uint4*)&Cs[r * LDA + kc * 8];
    }

    // ---- per-graph + global stats (scr aliases saff/taff; gather is done) ----
    {
        float* scr = saff;
        int c = tid & 127;
        int rbase = (tid >> 7) * 32;
        int curg = sb[rbase];
        float rs = 0.f, rss = 0.f;
        float ts = 0.f, tss = 0.f;
        for (int r = rbase; r < rbase + 32; ++r) {
            int g = sb[r];
            if (g < 0) break;
            if (g != curg) {
                atomicAdd(&gsum[curg * 128 + c], rs);
                atomicAdd(&gssq[curg * 128 + c], rss);
                rs = 0.f; rss = 0.f; curg = g;
            }
            float v = h2f(Cs[r * LDA + c]);
            rs += v; rss += v * v;
            ts += v; tss += v * v;
        }
        if (curg >= 0) {
            atomicAdd(&gsum[curg * 128 + c], rs);
            atomicAdd(&gssq[curg * 128 + c], rss);
        }
        if (tid >= 128) { scr[c] = ts; taff[c] = tss; }
        __syncthreads();   // b6
        if (tid < 128) {
            float* part = bnpart_out + (blockIdx.x & (NPART - 1)) * 256;
            atomicAdd(&part[c], ts + scr[c]);
            atomicAdd(&part[128 + c], tss + taff[c]);
        }
    }
}

// ---------------- combine (BN affine inline; graph sizes from gstart) -------------

__global__ __launch_bounds__(256) void combine(const float* __restrict__ gsum,
                                               const float* __restrict__ bnstat,
                                               const int* __restrict__ gstart,
                                               const float* __restrict__ gamma,
                                               const float* __restrict__ beta,
                                               const float* __restrict__ LW,
                                               const float* __restrict__ LB,
                                               float* __restrict__ out) {
    int gid = blockIdx.x * 256 + threadIdx.x;
    if (gid >= N_GRAPHS * 128) return;
    int g = gid >> 7;
    int d = gid & 127;
    float c = (float)(gstart[g + 1] - gstart[g]);
    float o = c * LB[0];
    const float invN = 1.0f / (float)N_NODES;
    #pragma unroll
    for (int l = 0; l < N_LAYERS; ++l) {
        const float* part = bnstat + l * NPART * 256;
        float sum = 0.f, ssq = 0.f;
        #pragma unroll
        for (int p = 0; p < NPART; ++p) {
            sum += part[p * 256 + d];
            ssq += part[p * 256 + 128 + d];
        }
        float m = sum * invN;
        float var = ssq * invN - m * m;
        float s = gamma[l * 128 + d] * rsqrtf(var + BN_EPS);
        float t = beta[l * 128 + d] - m * s;
        o += LW[l] * (s * gsum[(l * N_GRAPHS + g) * 128 + d] + c * t);
    }
    out[gid] = o;
}

// ---------------- host launcher ----------------

extern "C" void kernel_launch(void* const* d_in, const int* in_sizes, int n_in,
                              void* d_out, int out_size, void* d_ws, size_t ws_size,
                              hipStream_t stream) {
    const float* x      = (const float*)d_in[0];
    const int*   ei     = (const int*)d_in[1];
    const int*   batch  = (const int*)d_in[2];
    const float* ini_w1 = (const float*)d_in[3];
    const float* ini_b1 = (const float*)d_in[4];
    const float* ini_w2 = (const float*)d_in[5];
    const float* ini_b2 = (const float*)d_in[6];
    const float* gw1    = (const float*)d_in[7];
    const float* gb1    = (const float*)d_in[8];
    const float* gw2    = (const float*)d_in[9];
    const float* gb2    = (const float*)d_in[10];
    const float* gamma  = (const float*)d_in[11];
    const float* beta   = (const float*)d_in[12];
    const float* lw     = (const float*)d_in[13];
    const float* lb     = (const float*)d_in[14];
    float* out = (float*)d_out;

    char* p = (char*)d_ws;
    auto carve = [&](size_t bytes) -> char* {
        char* q = p;
        p += (bytes + 255) & ~(size_t)255;
        return q;
    };
    ushort* z0    = (ushort*)carve(sizeof(ushort) * N_NODES * DIM);
    ushort* z1    = (ushort*)carve(sizeof(ushort) * N_NODES * DIM);
    float* bnstat = (float*)carve(sizeof(float) * BN_FLOATS);
    float* gsum   = (float*)carve(sizeof(float) * N_LAYERS * N_GRAPHS * DIM);
    float* gssq   = (float*)carve(sizeof(float) * N_LAYERS * N_GRAPHS * DIM);
    short* wbf    = (short*)carve(sizeof(short) * 10 * 128 * 128);
    int* gstart   = (int*)carve(sizeof(int) * (N_GRAPHS + 1));
    int* cnt      = (int*)carve(sizeof(int) * N_NODES);
    ushort* slot  = (ushort*)carve(sizeof(ushort) * (N_NODES + 64) * SLOT_CAP);
    int* bcnt     = (int*)carve(sizeof(int) * NBLK_BIN * NBKT);
    uint* bpool   = (uint*)carve(sizeof(uint) * NBKT * NBLK_BIN * BCAP);  // 6.4 MB

    const int* src = ei;
    const int* dst = ei + N_EDGES;

    prep<<<TWB + NBLK_BIN + GSTART_BLOCKS + ZERO_BLOCKS, 256, 0, stream>>>(
        ini_w1, ini_w2, gw1, gw2, wbf, bnstat,
        src, dst, batch, bcnt, bpool, gstart, gsum, gssq);

    ini_fused<<<GBLOCKS + NBKT, 256, 0, stream>>>(
        x, wbf, ini_b1, wbf + 16384, ini_b2, z0,
        bpool, bcnt, cnt, slot);

    ushort* zprev = z0;
    ushort* znext = z1;
    for (int i = 0; i < N_LAYERS; ++i) {
        const float* bp_in = (i == 0) ? nullptr : bnstat + (i - 1) * NPART * 256;
        const float* gptr  = (i == 0) ? gamma : gamma + (i - 1) * DIM;
        const float* bptr  = (i == 0) ? beta : beta + (i - 1) * DIM;
        gin_fused<<<GBLOCKS, 256, 0, stream>>>(
            zprev, cnt, slot, bp_in, gptr, bptr,
            wbf + (2 + i) * 16384, gb1 + i * DIM,
            wbf + (6 + i) * 16384, gb2 + i * DIM, znext, batch,
            gsum + i * N_GRAPHS * DIM, gssq + i * N_GRAPHS * DIM,
            bnstat + i * NPART * 256);
        ushort* tmp = zprev; zprev = znext; znext = tmp;
    }
    combine<<<(N_GRAPHS * 128 + 255) / 256, 256, 0, stream>>>(
        gsum, bnstat, gstart, gamma, beta, lw, lb, out);
}